// Round 3
// baseline (414.768 us; speedup 1.0000x reference)
//
#include <hip/hip_runtime.h>

#define BB 16
#define CC 32
#define HH 256
#define WW 256

#define TW 32     // tile width (pixels) = MFMA N
#define TH 8      // tile rows per block (4 waves x 2 rows)
#define CIP 20    // padded ushorts per (y,x) per 16-ci chunk: 40 B = 10 words -> 2-way banks (free), 8B-aligned

typedef short bf16x8 __attribute__((ext_vector_type(8)));
typedef float f32x16 __attribute__((ext_vector_type(16)));

struct alignas(8)  U2 { unsigned x, y; };
struct alignas(16) U4 { U2 lo, hi; };

__device__ __forceinline__ unsigned short f2bf(float f) {
    unsigned u = __float_as_uint(f);
    u += 0x7fffu + ((u >> 16) & 1u);   // RNE
    return (unsigned short)(u >> 16);
}

// wq[layer][st(18)][half(2)][co(32)][j(8)], value = w[co][ci][pos]
// st = pos*2 + c (c = 16-ci chunk), ci = c*16 + half*8 + j.  (identical to R2 table)
__global__ void wprep(const float* __restrict__ w1, const float* __restrict__ w2,
                      unsigned short* __restrict__ wq) {
    int idx = blockIdx.x * 256 + threadIdx.x;   // 0..9215
    if (idx >= 18 * 2 * 32 * 8) return;
    int j    = idx & 7;
    int n    = (idx >> 3) & 31;
    int half = (idx >> 8) & 1;
    int st   = idx >> 9;
    int c = st & 1, pos = st >> 1;
    int ci = c * 16 + half * 8 + j;
    int src = (n * CC + ci) * 9 + pos;
    wq[idx]        = f2bf(w1[src]);
    wq[9216 + idx] = f2bf(w2[src]);
}

// Implicit-GEMM conv3x3 (SAME) with fused bias*gate + relu.
// FIRST: in = fp32 NCHW x, out = bf16 NHWC h1.
// !FIRST: in = bf16 NHWC h1, out = fp32 NCHW (+= resid).
template<bool FIRST>
__global__ __launch_bounds__(256)
void conv_mfma(const void* __restrict__ in,
               const unsigned short* __restrict__ wq,
               const float* __restrict__ bias,
               const float* __restrict__ gate,
               const float* __restrict__ resid,
               void* __restrict__ out)
{
    __shared__ unsigned short xs[TH + 2][TW + 2][CIP];   // 13600 B (one 16-ci chunk)
    __shared__ float gs[CC], bs[CC];

    const int t  = threadIdx.x;
    const int b  = blockIdx.z;
    const int y0 = blockIdx.y * TH;
    const int x0 = blockIdx.x * TW;

    if (t < CC) {
        float gv = gate[b * CC + t];
        gs[t] = gv > 0.f ? gv : 0.f;
        bs[t] = bias[t];
    }

    const int lane = t & 63;
    const int wv   = t >> 6;       // wave 0..3
    const int n    = lane & 31;    // MFMA pixel lane / co lane
    const int half = lane >> 5;
    const int r0 = wv * 2, r1 = wv * 2 + 1;

    f32x16 acc0 = {0,0,0,0,0,0,0,0,0,0,0,0,0,0,0,0};
    f32x16 acc1 = {0,0,0,0,0,0,0,0,0,0,0,0,0,0,0,0};

    #pragma unroll
    for (int c = 0; c < 2; ++c) {
        if (c) __syncthreads();      // chunk-0 compute done before overwrite

        // per-chunk weight frags: 9 x 16 B, L2-hot
        bf16x8 wf[9];
        #pragma unroll
        for (int pos = 0; pos < 9; ++pos) {
            U4 w = ((const U4*)wq)[((pos * 2 + c) * 2 + half) * 32 + n];
            wf[pos] = __builtin_bit_cast(bf16x8, w);
        }

        // ---- stage chunk c: 10 x 34 pixels x 16 ci ----
        if (FIRST) {
            const float* x = (const float*)in;
            const size_t basep = ((size_t)b * CC + c * 16) * HH;
            // main 32 cols: coalesced 128 B rows
            {
                const int xcM = 1 + (t & 31);
                const int g   = t >> 5;
                const int gx  = x0 + (t & 31);
                #pragma unroll
                for (int i = 0; i < 20; ++i) {
                    int p  = g + 8 * i;       // 0..159
                    int y  = p >> 4;          // 0..9
                    int ci = p & 15;
                    int gy = y0 + y - 1;
                    float v = 0.f;
                    if ((unsigned)gy < HH)
                        v = x[(basep + (size_t)ci * HH + gy) * WW + gx];
                    xs[y][xcM][ci] = f2bf(v);
                }
            }
            // halo cols xc=0 and xc=33
            if (t < 64) {
                int side = t & 1;
                int r    = t >> 1;           // 0..31
                int xc   = side ? 33 : 0;
                int gx   = side ? (x0 + 32) : (x0 - 1);
                bool xok = (unsigned)gx < WW;
                #pragma unroll
                for (int i = 0; i < 5; ++i) {
                    int p  = r + 32 * i;     // 0..159
                    int y  = p >> 4;
                    int ci = p & 15;
                    int gy = y0 + y - 1;
                    float v = 0.f;
                    if (xok && (unsigned)gy < HH)
                        v = x[(basep + (size_t)ci * HH + gy) * WW + gx];
                    xs[y][xc][ci] = f2bf(v);
                }
            }
        } else {
            const unsigned short* h = (const unsigned short*)in;
            // 10*34 pixels x 16 B half-chunks = 680 U4 loads
            #pragma unroll
            for (int i = 0; i < 3; ++i) {
                int idx = t + 256 * i;
                if (idx < 680) {
                    int q   = idx & 1;
                    int pix = idx >> 1;          // 0..339
                    int y   = pix / 34;
                    int xc  = pix - y * 34;
                    int gy = y0 + y - 1, gx = x0 + xc - 1;
                    U4 v; v.lo = {0u, 0u}; v.hi = {0u, 0u};
                    if ((unsigned)gy < HH && (unsigned)gx < WW)
                        v = *(const U4*)(h + (((size_t)b * HH + gy) * WW + gx) * CC + c * 16 + q * 8);
                    *(U2*)&xs[y][xc][q * 8]     = v.lo;
                    *(U2*)&xs[y][xc][q * 8 + 4] = v.hi;
                }
            }
        }
        __syncthreads();

        // ---- 9 positions x 2 rows MFMA ----
        #pragma unroll
        for (int pos = 0; pos < 9; ++pos) {
            const int kh = pos / 3, kw = pos - kh * 3;
            const unsigned short* pa = &xs[r0 + kh][n + kw][half * 8];
            const unsigned short* pb = &xs[r1 + kh][n + kw][half * 8];
            U4 xa, xb;
            xa.lo = *(const U2*)pa;       xa.hi = *(const U2*)(pa + 4);
            xb.lo = *(const U2*)pb;       xb.hi = *(const U2*)(pb + 4);
            acc0 = __builtin_amdgcn_mfma_f32_32x32x16_bf16(wf[pos], __builtin_bit_cast(bf16x8, xa), acc0, 0, 0, 0);
            acc1 = __builtin_amdgcn_mfma_f32_32x32x16_bf16(wf[pos], __builtin_bit_cast(bf16x8, xb), acc1, 0, 0, 0);
        }
    }

    // ---- epilogue: D[m=co][n=pixel], co = (reg&3) + 8*(reg>>2) + 4*half ----
    if (FIRST) {
        unsigned short* o = (unsigned short*)out;
        size_t p0 = (((size_t)b * HH + y0 + r0) * WW + x0 + n) * CC;
        size_t p1 = (((size_t)b * HH + y0 + r1) * WW + x0 + n) * CC;
        #pragma unroll
        for (int q = 0; q < 4; ++q) {
            unsigned short a0[4], a1[4];
            #pragma unroll
            for (int r = 0; r < 4; ++r) {
                int reg = q * 4 + r;
                int co  = r + 8 * q + 4 * half;
                float u0 = (acc0[reg] + bs[co]) * gs[co];
                float u1 = (acc1[reg] + bs[co]) * gs[co];
                a0[r] = f2bf(fmaxf(u0, 0.f));
                a1[r] = f2bf(fmaxf(u1, 0.f));
            }
            U2 w0, w1;
            w0.x = (unsigned)a0[0] | ((unsigned)a0[1] << 16);
            w0.y = (unsigned)a0[2] | ((unsigned)a0[3] << 16);
            w1.x = (unsigned)a1[0] | ((unsigned)a1[1] << 16);
            w1.y = (unsigned)a1[2] | ((unsigned)a1[3] << 16);
            *(U2*)(o + p0 + q * 8 + half * 4) = w0;
            *(U2*)(o + p1 + q * 8 + half * 4) = w1;
        }
    } else {
        float* o = (float*)out;
        #pragma unroll
        for (int reg = 0; reg < 16; ++reg) {
            int co = (reg & 3) + 8 * (reg >> 2) + 4 * half;
            size_t i0 = (((size_t)b * CC + co) * HH + y0 + r0) * WW + x0 + n;
            size_t i1 = (((size_t)b * CC + co) * HH + y0 + r1) * WW + x0 + n;
            float v0 = (acc0[reg] + bs[co]) * gs[co];
            float v1 = (acc1[reg] + bs[co]) * gs[co];
            o[i0] = fmaxf(v0, 0.f) + resid[i0];
            o[i1] = fmaxf(v1, 0.f) + resid[i1];
        }
    }
}

extern "C" void kernel_launch(void* const* d_in, const int* in_sizes, int n_in,
                              void* d_out, int out_size, void* d_ws, size_t ws_size,
                              hipStream_t stream) {
    const float* x  = (const float*)d_in[0];
    const float* gv = (const float*)d_in[1];
    const float* w1 = (const float*)d_in[2];
    const float* b1 = (const float*)d_in[3];
    const float* w2 = (const float*)d_in[4];
    const float* b2 = (const float*)d_in[5];
    float* out = (float*)d_out;

    unsigned short* h1 = (unsigned short*)d_ws;          // bf16 NHWC intermediate: 64 MiB
    unsigned short* wq = h1 + (size_t)BB * HH * WW * CC; // 2 x 9216 bf16 frag tables

    wprep<<<36, 256, 0, stream>>>(w1, w2, wq);

    dim3 grid(WW / TW, HH / TH, BB);  // (8, 32, 16) = 4096 blocks
    conv_mfma<true ><<<grid, 256, 0, stream>>>(x,  wq,        b1, gv, nullptr, h1);
    conv_mfma<false><<<grid, 256, 0, stream>>>(h1, wq + 9216, b2, gv, x,       out);
}